// Round 15
// baseline (6731.739 us; speedup 1.0000x reference)
//
#include <hip/hip_runtime.h>

typedef float f32x4 __attribute__((ext_vector_type(4)));
typedef _Float16 f16x2 __attribute__((ext_vector_type(2)));
typedef _Float16 f16x4 __attribute__((ext_vector_type(4)));
typedef _Float16 f16x8 __attribute__((ext_vector_type(8)));

#define BB 64
#define TT 1024
#define DIN 128
#define NB 256
#define KW 5
#define HID 512
#define LL 510
#define LT 32
#define ROWS 2048         // 4*HID
#define BPB 4             // blocks per batch
#define PRQ 512           // rows per block (one gate)
#define RGQ 128           // row-groups (4 rows) per block
#define CS 16             // xp chunk size (timesteps)
#define NHH4 (PRQ*HID)    // 262144 halves per quarter (2^18)
#define NIH4 (PRQ*NB)     // 131072 halves per quarter (2^17)
#define EPS 1e-5f

__device__ __forceinline__ float sigm(float x) { return 1.f/(1.f + expf(-x)); }

#if __has_builtin(__builtin_amdgcn_fdot2)
#define FDOT2(a, b, c) __builtin_amdgcn_fdot2((a), (b), (c), false)
#else
#define FDOT2(a, b, c) ((float)(a)[0]*(float)(b)[0] + (float)(a)[1]*(float)(b)[1] + (c))
#endif
#define SH(w, i) __builtin_shufflevector((w), (w), 2*(i), 2*(i)+1)

// ---------------- coherent helpers (sc0 sc1: write-through / bypass loads) --------
__device__ __forceinline__ void st16_sys(float* p, f32x4 v) {
  asm volatile("global_store_dwordx4 %0, %1, off sc0 sc1" :: "v"(p), "v"(v) : "memory");
}
__device__ __forceinline__ void st4_sys_u32(unsigned* p, unsigned v) {
  asm volatile("global_store_dword %0, %1, off sc0 sc1" :: "v"(p), "v"(v) : "memory");
}
__device__ __forceinline__ unsigned ld4_sys_u32(const unsigned* p) {
  unsigned v;
  asm volatile("global_load_dword %0, %1, off sc0 sc1\n\ts_waitcnt vmcnt(0)"
               : "=v"(v) : "v"(p) : "memory");
  return v;
}
__device__ __forceinline__ void ld16x3_sys(const float* a0, const float* a1,
                                           const float* a2,
                                           f32x4& r0, f32x4& r1, f32x4& r2) {
  asm volatile(
      "global_load_dwordx4 %0, %3, off sc0 sc1\n\t"
      "global_load_dwordx4 %1, %4, off sc0 sc1\n\t"
      "global_load_dwordx4 %2, %5, off sc0 sc1\n\t"
      "s_waitcnt vmcnt(0)"
      : "=&v"(r0), "=&v"(r1), "=&v"(r2)
      : "v"(a0), "v"(a1), "v"(a2)
      : "memory");
}

// ---- prep: pack W_hh / W_ih per quarter into fp16 dot2 layout (round-9 layout) ----
__global__ __launch_bounds__(256) void prep_kernel(
    const float* __restrict__ wih, const float* __restrict__ whh,
    const float* __restrict__ bih, const float* __restrict__ bhh,
    _Float16* __restrict__ whhP4, _Float16* __restrict__ wihP4,
    float* __restrict__ biasv)
{
  const int e = blockIdx.x*256 + threadIdx.x;
  if (e < 4*NHH4) {
    const int p = e >> 18, e2 = e & (NHH4-1);
    const int kp = e2 >> 10, rg = (e2 >> 3) & 127, s = e2 & 7;
    const int r = (p << 9) + 4*rg + (s >> 1), k = 2*kp + (s & 1);
    whhP4[e] = (_Float16)whh[(size_t)r*HID + k];
  } else if (e < 4*NHH4 + 4*NIH4) {
    const int f = e - 4*NHH4;
    const int p = f >> 17, f2 = f & (NIH4-1);
    const int kp = f2 >> 10, rg = (f2 >> 3) & 127, s = f2 & 7;
    const int r = (p << 9) + 4*rg + (s >> 1), k = 2*kp + (s & 1);
    wihP4[f] = (_Float16)wih[(size_t)r*NB + k];
  } else if (e < 4*NHH4 + 4*NIH4 + ROWS) {
    const int r = e - 4*NHH4 - 4*NIH4;
    biasv[r] = bih[r] + bhh[r];
  }
}

// ---------------- Conv1d + ReLU + BatchNorm (eval) -> seq[B][L][NB] ----------------
__global__ __launch_bounds__(256) void conv_kernel(
    const float* __restrict__ x, const float* __restrict__ cw,
    const float* __restrict__ cb, const float* __restrict__ gma,
    const float* __restrict__ bta, const float* __restrict__ bmean,
    const float* __restrict__ bvar, float* __restrict__ seq)
{
  __shared__ float xt[2*LT+3][DIN];
  const int b = blockIdx.y, lc = blockIdx.x, tid = threadIdx.x;
  const int l0 = lc*LT, t0 = l0*2;

  const float4* x4 = (const float4*)(x + ((size_t)b*TT + t0)*DIN);
  for (int i = tid; i < (2*LT+3)*(DIN/4); i += 256) {
    const int r = i >> 5, c = i & 31;
    float4 v = make_float4(0.f, 0.f, 0.f, 0.f);
    if (t0 + r < TT) v = x4[(size_t)r*(DIN/4) + c];
    ((float4*)xt[r])[c] = v;
  }
  __syncthreads();

  const int f = tid;
  float acc[LT];
#pragma unroll
  for (int l = 0; l < LT; ++l) acc[l] = 0.f;

  const float* wr = cw + (size_t)f*(DIN*KW);
  for (int d = 0; d < DIN; ++d) {
    float xr[2*LT+3];
#pragma unroll
    for (int r = 0; r < 2*LT+3; ++r) xr[r] = xt[r][d];
#pragma unroll
    for (int k = 0; k < KW; ++k) {
      const float w = wr[d*KW + k];
#pragma unroll
      for (int l = 0; l < LT; ++l) acc[l] += w * xr[2*l + k];
    }
  }

  const float bias  = cb[f];
  const float scale = gma[f] * rsqrtf(bvar[f] + EPS);
  const float shift = bta[f] - bmean[f]*scale;
#pragma unroll
  for (int l = 0; l < LT; ++l) {
    const int ll = l0 + l;
    if (ll < LL) {
      float y = acc[l] + bias;
      y = fmaxf(y, 0.f);
      seq[((size_t)b*LL + ll)*NB + f] = y*scale + shift;
    }
  }
}

// ---------------- SkipLSTM recurrence: 4 blocks per batch (round-9 protocol) ------
// 256 blocks x 1024 threads; block (b = blk>>2, p = blk&3) owns gate p.
// vs round 9: each thread's FIRST 16 k-pair weight tiles (64 VGPRs) hoisted into
// registers. __launch_bounds__(1024, 4) is REQUIRED: without the waves/EU arg the
// compiler caps at 64 VGPRs chasing useless occupancy (grid==CU count) and spills
// wreg to scratch -> 8.6 GB/launch of HBM scratch traffic (round-14 regression).
// 16-wave block at 4 waves/EU = 1 block/CU -> 128-VGPR budget; 56+64=120 fits.
__global__ __launch_bounds__(1024, 4) void rec_kernel(
    const float* __restrict__ seq, const _Float16* __restrict__ whhP4,
    const _Float16* __restrict__ wihP4, const float* __restrict__ biasv,
    const float* __restrict__ wu, const float* __restrict__ bu,
    float* __restrict__ gx, unsigned* __restrict__ flags,
    float* __restrict__ out)
{
  __shared__ float xp[CS][PRQ];               // 32 KB
  __shared__ f16x2 seqc[CS][NB/2];            //  8 KB
  __shared__ alignas(16) _Float16 zs[HID];    //  1 KB (h, fp16)
  __shared__ f32x4 part[7][RGQ];              // 14 KB
  __shared__ float gown[PRQ];                 //  2 KB (own activated gate)
  __shared__ f32x4 c_s[128];                  //  2 KB (cell, f32)
  __shared__ float pw[2];
  __shared__ int   u_lds;

  const int tid = threadIdx.x;
  const int rg  = tid & 127, kh = tid >> 7;   // kh in [0,8)
  const int blk = blockIdx.x, b = blk >> 2, p = blk & 3;
  const float* seqb = seq + (size_t)b*LL*NB;
  const _Float16* whhB = whhP4 + (size_t)p*NHH4;
  const _Float16* wihB = wihP4 + (size_t)p*NIH4;
  float* gx_b = gx + (size_t)b*BPB*2*PRQ;     // [4 blocks][2 buf][512]
  unsigned* flags_b = flags + (size_t)b*BPB*32;

  f32x4 bias4 = {0.f,0.f,0.f,0.f};
  if (kh == 0) bias4 = ((const f32x4*)biasv)[p*RGQ + rg];
  f32x4 wu4 = {0.f,0.f,0.f,0.f};
  if (tid < 128) wu4 = ((const f32x4*)wu)[tid];
  const float buv = bu[0];
  f32x4 hreg = {0.f,0.f,0.f,0.f};

  // ---- first 16 k-pair tiles of this thread's k-slice in registers (64 VGPRs) ----
  f16x8 wreg[16];
  {
    const f16x8* wp0 = (const f16x8*)whhB + ((size_t)(32*kh))*RGQ + rg;
#pragma unroll
    for (int i = 0; i < 16; ++i) wreg[i] = wp0[(size_t)i*RGQ];
  }

  float ut_r = 1.f, dot_r = 0.f;
  int ustep = 0;

  if (tid < 128) {
    *(f16x4*)(zs + 4*tid) = (f16x4){(_Float16)0,(_Float16)0,(_Float16)0,(_Float16)0};
    c_s[tid] = f32x4{0.f,0.f,0.f,0.f};
  }
  if (tid == 0) u_lds = 1;
  __syncthreads();

  for (int t0 = 0; t0 < LL; t0 += CS) {
    // ---- stage x chunk as fp16 pairs (each thread 2 slots) ----
    {
      const int tt = tid >> 7, kp = tid & 127;
#pragma unroll
      for (int o = 0; o < CS; o += 8) {
        const int ttt = tt + o;
        f16x2 v = {(_Float16)0, (_Float16)0};
        if (t0 + ttt < LL) {
          const float* sp = seqb + (size_t)(t0+ttt)*NB + 2*kp;
          v[0] = (_Float16)sp[0]; v[1] = (_Float16)sp[1];
        }
        seqc[ttt][kp] = v;
      }
    }
    __syncthreads();

    // ---- xp chunk GEMM: thread (rg, kh) -> rows 4rg..4rg+3, timesteps 2kh,2kh+1 --
    {
      f32x4 acc[2] = {{0,0,0,0},{0,0,0,0}};
      const f16x8* wp = (const f16x8*)wihB + rg;
#pragma unroll 4
      for (int kp = 0; kp < 128; ++kp) {
        const f16x8 w = wp[(size_t)kp*RGQ];
#pragma unroll
        for (int tt = 0; tt < 2; ++tt) {
          const f16x2 z = seqc[2*kh + tt][kp];
          acc[tt].x = FDOT2(SH(w,0), z, acc[tt].x);
          acc[tt].y = FDOT2(SH(w,1), z, acc[tt].y);
          acc[tt].z = FDOT2(SH(w,2), z, acc[tt].z);
          acc[tt].w = FDOT2(SH(w,3), z, acc[tt].w);
        }
      }
#pragma unroll
      for (int tt = 0; tt < 2; ++tt)
        *(f32x4*)&xp[2*kh + tt][4*rg] = acc[tt];
    }
    __syncthreads();

    const int tend = (t0 + CS < LL) ? t0 + CS : LL;
    for (int t = t0; t < tend; ++t) {
      const int u = u_lds;

      if (u) {
        ustep++;
        const int buf = ustep & 1;
        // ---- W_hh quarter-GEMV: kp 0..15 from REGISTERS, kp 16..31 streamed ----
        float a0 = 0.f, a1 = 0.f, a2 = 0.f, a3 = 0.f;
        {
          const _Float16* zp = zs + 64*kh;
#pragma unroll
          for (int i = 0; i < 16; ++i) {          // register half (kp = i)
            const f16x8 w = wreg[i];
            const f16x2 z = *(const f16x2*)(zp + 2*i);
            a0 = FDOT2(SH(w,0), z, a0);
            a1 = FDOT2(SH(w,1), z, a1);
            a2 = FDOT2(SH(w,2), z, a2);
            a3 = FDOT2(SH(w,3), z, a3);
          }
          const f16x8* wp = (const f16x8*)whhB + ((size_t)(32*kh))*RGQ + rg;
#pragma unroll 8
          for (int kp = 16; kp < 32; ++kp) {      // streamed half
            const f16x8 w = wp[(size_t)kp*RGQ];
            const f16x2 z = *(const f16x2*)(zp + 2*kp);
            a0 = FDOT2(SH(w,0), z, a0);
            a1 = FDOT2(SH(w,1), z, a1);
            a2 = FDOT2(SH(w,2), z, a2);
            a3 = FDOT2(SH(w,3), z, a3);
          }
        }
        if (kh) part[kh-1][rg] = f32x4{a0, a1, a2, a3};
        __syncthreads();                        // (1) partials

        if (kh == 0) {
          f32x4 v = f32x4{a0, a1, a2, a3} + bias4 + *(const f32x4*)&xp[t - t0][4*rg];
#pragma unroll
          for (int q = 0; q < 7; ++q) v += part[q][rg];
          f32x4 s;
          if (p == 2) {
            s.x = tanhf(v.x); s.y = tanhf(v.y); s.z = tanhf(v.z); s.w = tanhf(v.w);
          } else {
            s.x = sigm(v.x); s.y = sigm(v.y); s.z = sigm(v.z); s.w = sigm(v.w);
          }
          *(f32x4*)&gown[4*rg] = s;
          st16_sys(gx_b + ((size_t)p*2 + buf)*PRQ + 4*rg, s);
          asm volatile("s_waitcnt vmcnt(0)" ::: "memory");
        }
        __syncthreads();                        // (2) gx stores drained

        if (tid == 0) st4_sys_u32(flags_b + p*32, (unsigned)ustep);
        if (tid < 3) {
          const int q = (p + 1 + tid) & 3;
          const unsigned* fp = flags_b + q*32;
          unsigned f = ld4_sys_u32(fp);
          while (f < (unsigned)ustep) {
            __builtin_amdgcn_s_sleep(1);
            f = ld4_sys_u32(fp);
          }
        }
        __syncthreads();                        // (3) partners ready

        if (tid < 128) {
          const int j = 4*tid;
          const int q1 = (p+1)&3, q2 = (p+2)&3, q3 = (p+3)&3;
          f32x4 gv[4];
          gv[p] = *(const f32x4*)&gown[j];
          ld16x3_sys(gx_b + ((size_t)q1*2 + buf)*PRQ + j,
                     gx_b + ((size_t)q2*2 + buf)*PRQ + j,
                     gx_b + ((size_t)q3*2 + buf)*PRQ + j,
                     gv[q1], gv[q2], gv[q3]);
          const f32x4 i4 = gv[0], f4 = gv[1], g4 = gv[2], o4 = gv[3];
          const f32x4 c4 = c_s[tid];
          const f32x4 ct = f4*c4 + i4*g4;       // u==1 exact: c = cnew
          f32x4 ht;
          ht.x = o4.x*tanhf(ct.x); ht.y = o4.y*tanhf(ct.y);
          ht.z = o4.z*tanhf(ct.z); ht.w = o4.w*tanhf(ct.w);
          c_s[tid] = ct;
          hreg = ht;
          f16x4 hh; hh[0]=(_Float16)ht.x; hh[1]=(_Float16)ht.y;
          hh[2]=(_Float16)ht.z; hh[3]=(_Float16)ht.w;
          *(f16x4*)(zs + j) = hh;
          float pp = ct.x*wu4.x + ct.y*wu4.y + ct.z*wu4.z + ct.w*wu4.w;
#pragma unroll
          for (int off = 1; off < 64; off <<= 1) pp += __shfl_xor(pp, off);
          if ((tid & 63) == 0) pw[tid >> 6] = pp;
        }
        __syncthreads();                        // (4) h + wu-partials

        if (tid == 0) {
          dot_r = pw[0] + pw[1];
          const float du = sigm(dot_r + buv);
          ut_r = du;                            // u was 1: ut_next = du exactly
          u_lds = (int)rintf(ut_r);
        }
      } else {
        // ---- skip step: c,h,du unchanged; ut/u advance (identical in all 4) ----
        if (tid == 0) {
          const float du = sigm(dot_r + buv);
          ut_r = ut_r + fminf(du, 1.f - ut_r);
          u_lds = (int)rintf(ut_r);
        }
      }
      __syncthreads();                          // (5/end) u_lds, h visible
    }
  }

  if (p == 0 && tid < 128)
    *(f32x4*)(out + (size_t)b*HID + 4*tid) = hreg;
}

extern "C" void kernel_launch(void* const* d_in, const int* in_sizes, int n_in,
                              void* d_out, int out_size, void* d_ws, size_t ws_size,
                              hipStream_t stream) {
  const float* x    = (const float*)d_in[0];
  const float* cw   = (const float*)d_in[1];
  const float* cb   = (const float*)d_in[2];
  const float* gma  = (const float*)d_in[3];
  const float* bta  = (const float*)d_in[4];
  const float* bmean= (const float*)d_in[5];
  const float* bvar = (const float*)d_in[6];
  const float* wih  = (const float*)d_in[7];
  const float* whh  = (const float*)d_in[8];
  const float* bih  = (const float*)d_in[9];
  const float* bhh  = (const float*)d_in[10];
  const float* wu   = (const float*)d_in[11];
  const float* bu   = (const float*)d_in[12];
  float* out = (float*)d_out;

  float* ws       = (float*)d_ws;
  float* seq      = ws;                                    // 8,355,840 f
  _Float16* whhP4 = (_Float16*)(seq + (size_t)BB*LL*NB);   // 4*262144 h (2 MB)
  _Float16* wihP4 = whhP4 + (size_t)4*NHH4;                // 4*131072 h (1 MB)
  float* biasv    = (float*)(wihP4 + (size_t)4*NIH4);      // 2048 f
  float* gx       = biasv + ROWS;                          // 64*4*2*512 f (1 MB)
  unsigned* flags = (unsigned*)(gx + (size_t)BB*BPB*2*PRQ);// 64*4*32 u32 (32 KB)

  hipMemsetAsync(flags, 0, (size_t)BB*BPB*32*sizeof(unsigned), stream);

  hipLaunchKernelGGL(prep_kernel,
                     dim3((4*NHH4 + 4*NIH4 + ROWS + 255)/256), dim3(256),
                     0, stream, wih, whh, bih, bhh, whhP4, wihP4, biasv);
  hipLaunchKernelGGL(conv_kernel, dim3(16, 64), dim3(256), 0, stream,
                     x, cw, cb, gma, bta, bmean, bvar, seq);
  hipLaunchKernelGGL(rec_kernel, dim3(BPB*BB), dim3(1024), 0, stream,
                     seq, whhP4, wihP4, biasv, wu, bu, gx, flags, out);
}

// Round 16
// 4309.071 us; speedup vs baseline: 1.5622x; 1.5622x over previous
//
#include <hip/hip_runtime.h>

typedef float f32x2 __attribute__((ext_vector_type(2)));
typedef float f32x4 __attribute__((ext_vector_type(4)));
typedef _Float16 f16x2 __attribute__((ext_vector_type(2)));
typedef _Float16 f16x4 __attribute__((ext_vector_type(4)));

#define BB 64
#define TT 1024
#define DIN 128
#define NB 256
#define KW 5
#define HID 512
#define LL 510
#define LT 32
#define ROWS 2048         // 4*HID
#define BPB 4             // blocks per batch
#define PRQ 512           // local rows per block (4 gates x 128 units)
#define RGQ 128           // row-groups (4 rows) per block
#define CS 16             // xp chunk size (timesteps)
#define PAYF 128          // floats per (block,buf) payload slot (512B)
                          // halves [0,128) = h-slice; floats 64,65 = pw0,pw1
#define NHH4 (PRQ*HID)    // 262144 halves per quarter (2^18)
#define NIH4 (PRQ*NB)     // 131072 halves per quarter (2^17)
#define EPS 1e-5f

__device__ __forceinline__ float sigm(float x) { return 1.f/(1.f + expf(-x)); }

#if __has_builtin(__builtin_amdgcn_fdot2)
#define FDOT2(a, b, c) __builtin_amdgcn_fdot2((a), (b), (c), false)
#else
#define FDOT2(a, b, c) ((float)(a)[0]*(float)(b)[0] + (float)(a)[1]*(float)(b)[1] + (c))
#endif
#define SH(w, i) __builtin_shufflevector((w), (w), 2*(i), 2*(i)+1)

typedef _Float16 f16x8 __attribute__((ext_vector_type(8)));

// ---------------- coherent helpers (sc0 sc1: write-through / bypass loads) --------
__device__ __forceinline__ void st2_sys(_Float16* p, _Float16 v) {
  unsigned ui = (unsigned)__builtin_bit_cast(unsigned short, v);
  asm volatile("global_store_short %0, %1, off sc0 sc1" :: "v"(p), "v"(ui) : "memory");
}
__device__ __forceinline__ void st4f_sys(float* p, float v) {
  asm volatile("global_store_dword %0, %1, off sc0 sc1" :: "v"(p), "v"(v) : "memory");
}
__device__ __forceinline__ void st4_sys_u32(unsigned* p, unsigned v) {
  asm volatile("global_store_dword %0, %1, off sc0 sc1" :: "v"(p), "v"(v) : "memory");
}
__device__ __forceinline__ unsigned ld4_sys_u32(const unsigned* p) {
  unsigned v;
  asm volatile("global_load_dword %0, %1, off sc0 sc1\n\ts_waitcnt vmcnt(0)"
               : "=v"(v) : "v"(p) : "memory");
  return v;
}
__device__ __forceinline__ f32x4 ld16_sys1(const float* a) {
  f32x4 r;
  asm volatile("global_load_dwordx4 %0, %1, off sc0 sc1\n\ts_waitcnt vmcnt(0)"
               : "=v"(r) : "v"(a) : "memory");
  return r;
}
__device__ __forceinline__ void ld8x3_sys(const float* a0, const float* a1,
                                          const float* a2,
                                          f32x2& r0, f32x2& r1, f32x2& r2) {
  asm volatile(
      "global_load_dwordx2 %0, %3, off sc0 sc1\n\t"
      "global_load_dwordx2 %1, %4, off sc0 sc1\n\t"
      "global_load_dwordx2 %2, %5, off sc0 sc1\n\t"
      "s_waitcnt vmcnt(0)"
      : "=&v"(r0), "=&v"(r1), "=&v"(r2)
      : "v"(a0), "v"(a1), "v"(a2)
      : "memory");
}

// ---- prep: COLUMN-SPLIT packing. Quarter p owns units [128p,128p+128) for all
// 4 gates: local row rl in [0,512) -> global row r = (rl>>7)*512 + 128p + (rl&127).
// Same dot2 tile layout as round 9: e = ((kp*RGQ)+rg)*8+s, rl = 4rg+(s>>1),
// k = 2kp+(s&1). biasvP is remapped to quarter-local row order.
__global__ __launch_bounds__(256) void prep_kernel(
    const float* __restrict__ wih, const float* __restrict__ whh,
    const float* __restrict__ bih, const float* __restrict__ bhh,
    _Float16* __restrict__ whhP4, _Float16* __restrict__ wihP4,
    float* __restrict__ biasvP)
{
  const int e = blockIdx.x*256 + threadIdx.x;
  if (e < 4*NHH4) {
    const int p = e >> 18, e2 = e & (NHH4-1);
    const int kp = e2 >> 10, rg = (e2 >> 3) & 127, s = e2 & 7;
    const int rl = 4*rg + (s >> 1);
    const int r = ((rl >> 7) << 9) + (p << 7) + (rl & 127);
    const int k = 2*kp + (s & 1);
    whhP4[e] = (_Float16)whh[(size_t)r*HID + k];
  } else if (e < 4*NHH4 + 4*NIH4) {
    const int f = e - 4*NHH4;
    const int p = f >> 17, f2 = f & (NIH4-1);
    const int kp = f2 >> 10, rg = (f2 >> 3) & 127, s = f2 & 7;
    const int rl = 4*rg + (s >> 1);
    const int r = ((rl >> 7) << 9) + (p << 7) + (rl & 127);
    const int k = 2*kp + (s & 1);
    wihP4[f] = (_Float16)wih[(size_t)r*NB + k];
  } else if (e < 4*NHH4 + 4*NIH4 + ROWS) {
    const int idx = e - 4*NHH4 - 4*NIH4;
    const int p = idx >> 9, rl = idx & 511;
    const int r = ((rl >> 7) << 9) + (p << 7) + (rl & 127);
    biasvP[idx] = bih[r] + bhh[r];
  }
}

// ---------------- Conv1d + ReLU + BatchNorm (eval) -> seq[B][L][NB] ----------------
__global__ __launch_bounds__(256) void conv_kernel(
    const float* __restrict__ x, const float* __restrict__ cw,
    const float* __restrict__ cb, const float* __restrict__ gma,
    const float* __restrict__ bta, const float* __restrict__ bmean,
    const float* __restrict__ bvar, float* __restrict__ seq)
{
  __shared__ float xt[2*LT+3][DIN];
  const int b = blockIdx.y, lc = blockIdx.x, tid = threadIdx.x;
  const int l0 = lc*LT, t0 = l0*2;

  const float4* x4 = (const float4*)(x + ((size_t)b*TT + t0)*DIN);
  for (int i = tid; i < (2*LT+3)*(DIN/4); i += 256) {
    const int r = i >> 5, c = i & 31;
    float4 v = make_float4(0.f, 0.f, 0.f, 0.f);
    if (t0 + r < TT) v = x4[(size_t)r*(DIN/4) + c];
    ((float4*)xt[r])[c] = v;
  }
  __syncthreads();

  const int f = tid;
  float acc[LT];
#pragma unroll
  for (int l = 0; l < LT; ++l) acc[l] = 0.f;

  const float* wr = cw + (size_t)f*(DIN*KW);
  for (int d = 0; d < DIN; ++d) {
    float xr[2*LT+3];
#pragma unroll
    for (int r = 0; r < 2*LT+3; ++r) xr[r] = xt[r][d];
#pragma unroll
    for (int k = 0; k < KW; ++k) {
      const float w = wr[d*KW + k];
#pragma unroll
      for (int l = 0; l < LT; ++l) acc[l] += w * xr[2*l + k];
    }
  }

  const float bias  = cb[f];
  const float scale = gma[f] * rsqrtf(bvar[f] + EPS);
  const float shift = bta[f] - bmean[f]*scale;
#pragma unroll
  for (int l = 0; l < LT; ++l) {
    const int ll = l0 + l;
    if (ll < LL) {
      float y = acc[l] + bias;
      y = fmaxf(y, 0.f);
      seq[((size_t)b*LL + ll)*NB + f] = y*scale + shift;
    }
  }
}

// ---------------- SkipLSTM recurrence: COLUMN-SPLIT, 4 blocks per batch -----------
// 256 blocks x 1024 threads; block (b = blk>>2, p = blk&3) owns ALL 4 GATES for
// hidden units [128p,128p+128). State update is block-local (c in registers);
// the only exchange is the 128-unit h-slice (fp16, 256B) + 2 du-partials per
// block per update step — 8x smaller than round 9's gate exchange. Flag protocol
// verbatim from the passing round-9 kernel. du dot assembled in fixed p-order
// from per-block partials -> bitwise-identical u decisions in all 4 blocks.
__global__ __launch_bounds__(1024) void rec_kernel(
    const float* __restrict__ seq, const _Float16* __restrict__ whhP4,
    const _Float16* __restrict__ wihP4, const float* __restrict__ biasvP,
    const float* __restrict__ wu, const float* __restrict__ bu,
    float* __restrict__ pay, unsigned* __restrict__ flags,
    float* __restrict__ out)
{
  __shared__ float xp[CS][PRQ];               // 32 KB
  __shared__ f16x2 seqc[CS][NB/2];            //  8 KB
  __shared__ alignas(16) _Float16 zs[HID];    //  1 KB (full h, fp16)
  __shared__ f32x4 part[7][RGQ];              // 14 KB
  __shared__ float gown[PRQ];                 //  2 KB (own 4-gate activations)
  __shared__ float pw[2];
  __shared__ int   u_lds;

  const int tid = threadIdx.x;
  const int rg  = tid & 127, kh = tid >> 7;   // kh in [0,8)
  const int blk = blockIdx.x, b = blk >> 2, p = blk & 3;
  const float* seqb = seq + (size_t)b*LL*NB;
  const _Float16* whhB = whhP4 + (size_t)p*NHH4;
  const _Float16* wihB = wihP4 + (size_t)p*NIH4;
  float* pay_own = pay + (size_t)blk*2*PAYF;
  const float* pay_b = pay + (size_t)(b*BPB)*2*PAYF;
  unsigned* flags_b = flags + (size_t)b*BPB*32;

  f32x4 bias4 = {0.f,0.f,0.f,0.f};
  if (kh == 0) bias4 = ((const f32x4*)(biasvP + p*PRQ))[rg];
  const float wuj = (tid < 128) ? wu[128*p + tid] : 0.f;
  const float buv = bu[0];

  float c_reg = 0.f, h_out = 0.f;             // unit (tid) state, tid<128
  float ut_r = 1.f, dot_r = 0.f;              // thread-0 scalar state
  int ustep = 0;

  if (tid < 128)
    *(f16x4*)(zs + 4*tid) = (f16x4){(_Float16)0,(_Float16)0,(_Float16)0,(_Float16)0};
  if (tid == 0) u_lds = 1;
  __syncthreads();

  for (int t0 = 0; t0 < LL; t0 += CS) {
    // ---- stage x chunk as fp16 pairs ----
    {
      const int tt = tid >> 7, kp = tid & 127;
#pragma unroll
      for (int o = 0; o < CS; o += 8) {
        const int ttt = tt + o;
        f16x2 v = {(_Float16)0, (_Float16)0};
        if (t0 + ttt < LL) {
          const float* sp = seqb + (size_t)(t0+ttt)*NB + 2*kp;
          v[0] = (_Float16)sp[0]; v[1] = (_Float16)sp[1];
        }
        seqc[ttt][kp] = v;
      }
    }
    __syncthreads();

    // ---- xp chunk GEMM: thread (rg, kh) -> rows 4rg..4rg+3, timesteps 2kh,2kh+1 --
    {
      f32x4 acc[2] = {{0,0,0,0},{0,0,0,0}};
      const f16x8* wp = (const f16x8*)wihB + rg;
#pragma unroll 4
      for (int kp = 0; kp < 128; ++kp) {
        const f16x8 w = wp[(size_t)kp*RGQ];
#pragma unroll
        for (int tt = 0; tt < 2; ++tt) {
          const f16x2 z = seqc[2*kh + tt][kp];
          acc[tt].x = FDOT2(SH(w,0), z, acc[tt].x);
          acc[tt].y = FDOT2(SH(w,1), z, acc[tt].y);
          acc[tt].z = FDOT2(SH(w,2), z, acc[tt].z);
          acc[tt].w = FDOT2(SH(w,3), z, acc[tt].w);
        }
      }
#pragma unroll
      for (int tt = 0; tt < 2; ++tt)
        *(f32x4*)&xp[2*kh + tt][4*rg] = acc[tt];
    }
    __syncthreads();

    const int tend = (t0 + CS < LL) ? t0 + CS : LL;
    for (int t = t0; t < tend; ++t) {
      const int u = u_lds;

      if (u) {
        ustep++;
        const int buf = ustep & 1;
        // ---- W_hh quarter-GEMV: k-slice kh (32 k-pairs, streamed) ----
        float a0 = 0.f, a1 = 0.f, a2 = 0.f, a3 = 0.f;
        {
          const f16x8* wp = (const f16x8*)whhB + ((size_t)(32*kh))*RGQ + rg;
          const _Float16* zp = zs + 64*kh;
#pragma unroll 8
          for (int kp = 0; kp < 32; ++kp) {
            const f16x8 w = wp[(size_t)kp*RGQ];
            const f16x2 z = *(const f16x2*)(zp + 2*kp);
            a0 = FDOT2(SH(w,0), z, a0);
            a1 = FDOT2(SH(w,1), z, a1);
            a2 = FDOT2(SH(w,2), z, a2);
            a3 = FDOT2(SH(w,3), z, a3);
          }
        }
        if (kh) part[kh-1][rg] = f32x4{a0, a1, a2, a3};
        __syncthreads();                        // (1) k-partials

        if (kh == 0) {
          f32x4 v = f32x4{a0, a1, a2, a3} + bias4 + *(const f32x4*)&xp[t - t0][4*rg];
#pragma unroll
          for (int q = 0; q < 7; ++q) v += part[q][rg];
          const int gate = rg >> 5;             // local rows 4rg..4rg+3, gate = rl>>7
          f32x4 s;
          if (gate == 2) {
            s.x = tanhf(v.x); s.y = tanhf(v.y); s.z = tanhf(v.z); s.w = tanhf(v.w);
          } else {
            s.x = sigm(v.x); s.y = sigm(v.y); s.z = sigm(v.z); s.w = sigm(v.w);
          }
          *(f32x4*)&gown[4*rg] = s;
        }
        __syncthreads();                        // (2) gown ready

        // ---- local state update: unit jj = tid (c in register) ----
        if (tid < 128) {
          const int jj = tid;
          const float ig = gown[jj],       fg = gown[128 + jj];
          const float gg = gown[256 + jj], og = gown[384 + jj];
          const float ct = fg*c_reg + ig*gg;    // u==1 exact: c = cnew
          const float ht = og * tanhf(ct);
          c_reg = ct; h_out = ht;
          const _Float16 hh = (_Float16)ht;
          zs[128*p + jj] = hh;
          st2_sys((_Float16*)(pay_own + (size_t)buf*PAYF) + jj, hh);
          float pp = ct * wuj;
#pragma unroll
          for (int off = 1; off < 64; off <<= 1) pp += __shfl_xor(pp, off);
          if ((tid & 63) == 0) {
            pw[tid >> 6] = pp;
            st4f_sys(pay_own + (size_t)buf*PAYF + 64 + (tid >> 6), pp);
          }
          asm volatile("s_waitcnt vmcnt(0)" ::: "memory");
        }
        __syncthreads();                        // (3) payload drained

        // ---- flag: store own FIRST, then poll (round-9 protocol verbatim) ----
        if (tid == 0) st4_sys_u32(flags_b + p*32, (unsigned)ustep);
        if (tid < 3) {
          const int q = (p + 1 + tid) & 3;
          const unsigned* fp = flags_b + q*32;
          unsigned f = ld4_sys_u32(fp);
          while (f < (unsigned)ustep) {
            __builtin_amdgcn_s_sleep(1);
            f = ld4_sys_u32(fp);
          }
        }
        __syncthreads();                        // (4) partners ready

        // ---- partner h-slices -> zs; tid0 assembles du dot + u decision ----
        if (tid < 48) {
          const int q = tid >> 4, o = tid & 15;
          const int p2 = (p + 1 + q) & 3;
          const float* pp2 = pay_b + ((size_t)p2*2 + buf)*PAYF;
          const f32x4 r = ld16_sys1(pp2 + o*4);
          *(f32x4*)&zs[128*p2 + o*8] = r;
        }
        if (tid == 0) {
          const int q1 = (p+1)&3, q2 = (p+2)&3, q3 = (p+3)&3;
          f32x2 r1, r2, r3;
          ld8x3_sys(pay_b + ((size_t)q1*2 + buf)*PAYF + 64,
                    pay_b + ((size_t)q2*2 + buf)*PAYF + 64,
                    pay_b + ((size_t)q3*2 + buf)*PAYF + 64, r1, r2, r3);
          float dsum[4];
          dsum[p]  = pw[0] + pw[1];
          dsum[q1] = r1.x + r1.y;
          dsum[q2] = r2.x + r2.y;
          dsum[q3] = r3.x + r3.y;
          const float dot = dsum[0] + dsum[1] + dsum[2] + dsum[3];
          const float du = sigm(dot + buv);
          ut_r = du; dot_r = dot;               // u was 1: ut_next = du exactly
          u_lds = (int)rintf(du);
        }
      } else {
        // ---- skip step: c,h,du unchanged; ut/u advance (identical in all 4) ----
        if (tid == 0) {
          const float du = sigm(dot_r + buv);
          ut_r = ut_r + fminf(du, 1.f - ut_r);
          u_lds = (int)rintf(ut_r);
        }
      }
      __syncthreads();                          // (5/end) u_lds, zs visible
    }
  }

  // each block writes ITS disjoint 128-unit slice
  if (tid < 128)
    out[(size_t)b*HID + 128*p + tid] = h_out;
}

extern "C" void kernel_launch(void* const* d_in, const int* in_sizes, int n_in,
                              void* d_out, int out_size, void* d_ws, size_t ws_size,
                              hipStream_t stream) {
  const float* x    = (const float*)d_in[0];
  const float* cw   = (const float*)d_in[1];
  const float* cb   = (const float*)d_in[2];
  const float* gma  = (const float*)d_in[3];
  const float* bta  = (const float*)d_in[4];
  const float* bmean= (const float*)d_in[5];
  const float* bvar = (const float*)d_in[6];
  const float* wih  = (const float*)d_in[7];
  const float* whh  = (const float*)d_in[8];
  const float* bih  = (const float*)d_in[9];
  const float* bhh  = (const float*)d_in[10];
  const float* wu   = (const float*)d_in[11];
  const float* bu   = (const float*)d_in[12];
  float* out = (float*)d_out;

  float* ws       = (float*)d_ws;
  float* seq      = ws;                                    // 8,355,840 f
  _Float16* whhP4 = (_Float16*)(seq + (size_t)BB*LL*NB);   // 4*262144 h (2 MB)
  _Float16* wihP4 = whhP4 + (size_t)4*NHH4;                // 4*131072 h (1 MB)
  float* biasvP   = (float*)(wihP4 + (size_t)4*NIH4);      // 2048 f
  float* pay      = biasvP + ROWS;                         // 256*2*128 f (256 KB)
  unsigned* flags = (unsigned*)(pay + (size_t)BPB*BB*2*PAYF); // 256*32 u32

  hipMemsetAsync(flags, 0, (size_t)BPB*BB*32*sizeof(unsigned), stream);

  hipLaunchKernelGGL(prep_kernel,
                     dim3((4*NHH4 + 4*NIH4 + ROWS + 255)/256), dim3(256),
                     0, stream, wih, whh, bih, bhh, whhP4, wihP4, biasvP);
  hipLaunchKernelGGL(conv_kernel, dim3(16, 64), dim3(256), 0, stream,
                     x, cw, cb, gma, bta, bmean, bvar, seq);
  hipLaunchKernelGGL(rec_kernel, dim3(BPB*BB), dim3(1024), 0, stream,
                     seq, whhP4, wihP4, biasvP, wu, bu, pay, flags, out);
}

// Round 17
// 4304.485 us; speedup vs baseline: 1.5639x; 1.0011x over previous
//
#include <hip/hip_runtime.h>

typedef float f32x2 __attribute__((ext_vector_type(2)));
typedef float f32x4 __attribute__((ext_vector_type(4)));
typedef _Float16 f16x2 __attribute__((ext_vector_type(2)));
typedef _Float16 f16x4 __attribute__((ext_vector_type(4)));

#define BB 64
#define TT 1024
#define DIN 128
#define NB 256
#define KW 5
#define HID 512
#define LL 510
#define LT 32
#define ROWS 2048         // 4*HID
#define BPB 4             // blocks per batch
#define PRQ 512           // local rows per block (4 gates x 128 units)
#define RGQ 128           // row-groups (4 rows) per block
#define CS 16             // xp chunk size (timesteps)
#define PAYF 128          // floats per (block,buf) payload slot (512B)
                          // halves [0,128) = h-slice; floats 64,65 = pw0,pw1
#define NHH4 (PRQ*HID)    // 262144 halves per quarter (2^18)
#define NIH4 (PRQ*NB)     // 131072 halves per quarter (2^17)
#define EPS 1e-5f

__device__ __forceinline__ float sigm(float x) { return 1.f/(1.f + expf(-x)); }

#if __has_builtin(__builtin_amdgcn_fdot2)
#define FDOT2(a, b, c) __builtin_amdgcn_fdot2((a), (b), (c), false)
#else
#define FDOT2(a, b, c) ((float)(a)[0]*(float)(b)[0] + (float)(a)[1]*(float)(b)[1] + (c))
#endif
#define SH(w, i) __builtin_shufflevector((w), (w), 2*(i), 2*(i)+1)

typedef _Float16 f16x8 __attribute__((ext_vector_type(8)));

// ---------------- coherent helpers (sc0 sc1: write-through / bypass loads) --------
__device__ __forceinline__ void st2_sys(_Float16* p, _Float16 v) {
  unsigned ui = (unsigned)__builtin_bit_cast(unsigned short, v);
  asm volatile("global_store_short %0, %1, off sc0 sc1" :: "v"(p), "v"(ui) : "memory");
}
__device__ __forceinline__ void st4f_sys(float* p, float v) {
  asm volatile("global_store_dword %0, %1, off sc0 sc1" :: "v"(p), "v"(v) : "memory");
}
__device__ __forceinline__ void st4_sys_u32(unsigned* p, unsigned v) {
  asm volatile("global_store_dword %0, %1, off sc0 sc1" :: "v"(p), "v"(v) : "memory");
}
__device__ __forceinline__ unsigned ld4_sys_u32(const unsigned* p) {
  unsigned v;
  asm volatile("global_load_dword %0, %1, off sc0 sc1\n\ts_waitcnt vmcnt(0)"
               : "=v"(v) : "v"(p) : "memory");
  return v;
}
__device__ __forceinline__ f32x4 ld16_sys1(const float* a) {
  f32x4 r;
  asm volatile("global_load_dwordx4 %0, %1, off sc0 sc1\n\ts_waitcnt vmcnt(0)"
               : "=v"(r) : "v"(a) : "memory");
  return r;
}
__device__ __forceinline__ void ld8x3_sys(const float* a0, const float* a1,
                                          const float* a2,
                                          f32x2& r0, f32x2& r1, f32x2& r2) {
  asm volatile(
      "global_load_dwordx2 %0, %3, off sc0 sc1\n\t"
      "global_load_dwordx2 %1, %4, off sc0 sc1\n\t"
      "global_load_dwordx2 %2, %5, off sc0 sc1\n\t"
      "s_waitcnt vmcnt(0)"
      : "=&v"(r0), "=&v"(r1), "=&v"(r2)
      : "v"(a0), "v"(a1), "v"(a2)
      : "memory");
}

// ---- prep: COLUMN-SPLIT packing. Quarter p owns units [128p,128p+128) for all
// 4 gates: local row rl in [0,512) -> global row r = (rl>>7)*512 + 128p + (rl&127).
// Same dot2 tile layout as round 9: e = ((kp*RGQ)+rg)*8+s, rl = 4rg+(s>>1),
// k = 2kp+(s&1). biasvP is remapped to quarter-local row order.
__global__ __launch_bounds__(256) void prep_kernel(
    const float* __restrict__ wih, const float* __restrict__ whh,
    const float* __restrict__ bih, const float* __restrict__ bhh,
    _Float16* __restrict__ whhP4, _Float16* __restrict__ wihP4,
    float* __restrict__ biasvP)
{
  const int e = blockIdx.x*256 + threadIdx.x;
  if (e < 4*NHH4) {
    const int p = e >> 18, e2 = e & (NHH4-1);
    const int kp = e2 >> 10, rg = (e2 >> 3) & 127, s = e2 & 7;
    const int rl = 4*rg + (s >> 1);
    const int r = ((rl >> 7) << 9) + (p << 7) + (rl & 127);
    const int k = 2*kp + (s & 1);
    whhP4[e] = (_Float16)whh[(size_t)r*HID + k];
  } else if (e < 4*NHH4 + 4*NIH4) {
    const int f = e - 4*NHH4;
    const int p = f >> 17, f2 = f & (NIH4-1);
    const int kp = f2 >> 10, rg = (f2 >> 3) & 127, s = f2 & 7;
    const int rl = 4*rg + (s >> 1);
    const int r = ((rl >> 7) << 9) + (p << 7) + (rl & 127);
    const int k = 2*kp + (s & 1);
    wihP4[f] = (_Float16)wih[(size_t)r*NB + k];
  } else if (e < 4*NHH4 + 4*NIH4 + ROWS) {
    const int idx = e - 4*NHH4 - 4*NIH4;
    const int p = idx >> 9, rl = idx & 511;
    const int r = ((rl >> 7) << 9) + (p << 7) + (rl & 127);
    biasvP[idx] = bih[r] + bhh[r];
  }
}

// ---------------- Conv1d + ReLU + BatchNorm (eval) -> seq[B][L][NB] ----------------
__global__ __launch_bounds__(256) void conv_kernel(
    const float* __restrict__ x, const float* __restrict__ cw,
    const float* __restrict__ cb, const float* __restrict__ gma,
    const float* __restrict__ bta, const float* __restrict__ bmean,
    const float* __restrict__ bvar, float* __restrict__ seq)
{
  __shared__ float xt[2*LT+3][DIN];
  const int b = blockIdx.y, lc = blockIdx.x, tid = threadIdx.x;
  const int l0 = lc*LT, t0 = l0*2;

  const float4* x4 = (const float4*)(x + ((size_t)b*TT + t0)*DIN);
  for (int i = tid; i < (2*LT+3)*(DIN/4); i += 256) {
    const int r = i >> 5, c = i & 31;
    float4 v = make_float4(0.f, 0.f, 0.f, 0.f);
    if (t0 + r < TT) v = x4[(size_t)r*(DIN/4) + c];
    ((float4*)xt[r])[c] = v;
  }
  __syncthreads();

  const int f = tid;
  float acc[LT];
#pragma unroll
  for (int l = 0; l < LT; ++l) acc[l] = 0.f;

  const float* wr = cw + (size_t)f*(DIN*KW);
  for (int d = 0; d < DIN; ++d) {
    float xr[2*LT+3];
#pragma unroll
    for (int r = 0; r < 2*LT+3; ++r) xr[r] = xt[r][d];
#pragma unroll
    for (int k = 0; k < KW; ++k) {
      const float w = wr[d*KW + k];
#pragma unroll
      for (int l = 0; l < LT; ++l) acc[l] += w * xr[2*l + k];
    }
  }

  const float bias  = cb[f];
  const float scale = gma[f] * rsqrtf(bvar[f] + EPS);
  const float shift = bta[f] - bmean[f]*scale;
#pragma unroll
  for (int l = 0; l < LT; ++l) {
    const int ll = l0 + l;
    if (ll < LL) {
      float y = acc[l] + bias;
      y = fmaxf(y, 0.f);
      seq[((size_t)b*LL + ll)*NB + f] = y*scale + shift;
    }
  }
}

// ---------------- SkipLSTM recurrence: COLUMN-SPLIT, 4 blocks per batch -----------
// 256 blocks x 1024 threads; block (b = blk>>2, p = blk&3) owns ALL 4 GATES for
// hidden units [128p,128p+128). State update is block-local (c in registers);
// the only exchange is the 128-unit h-slice (fp16, 256B) + 2 du-partials per
// block per update step — 8x smaller than round 9's gate exchange. Flag protocol
// verbatim from the passing round-9 kernel. du dot assembled in fixed p-order
// from per-block partials -> bitwise-identical u decisions in all 4 blocks.
__global__ __launch_bounds__(1024) void rec_kernel(
    const float* __restrict__ seq, const _Float16* __restrict__ whhP4,
    const _Float16* __restrict__ wihP4, const float* __restrict__ biasvP,
    const float* __restrict__ wu, const float* __restrict__ bu,
    float* __restrict__ pay, unsigned* __restrict__ flags,
    float* __restrict__ out)
{
  __shared__ float xp[CS][PRQ];               // 32 KB
  __shared__ f16x2 seqc[CS][NB/2];            //  8 KB
  __shared__ alignas(16) _Float16 zs[HID];    //  1 KB (full h, fp16)
  __shared__ f32x4 part[7][RGQ];              // 14 KB
  __shared__ float gown[PRQ];                 //  2 KB (own 4-gate activations)
  __shared__ float pw[2];
  __shared__ int   u_lds;

  const int tid = threadIdx.x;
  const int rg  = tid & 127, kh = tid >> 7;   // kh in [0,8)
  const int blk = blockIdx.x, b = blk >> 2, p = blk & 3;
  const float* seqb = seq + (size_t)b*LL*NB;
  const _Float16* whhB = whhP4 + (size_t)p*NHH4;
  const _Float16* wihB = wihP4 + (size_t)p*NIH4;
  float* pay_own = pay + (size_t)blk*2*PAYF;
  const float* pay_b = pay + (size_t)(b*BPB)*2*PAYF;
  unsigned* flags_b = flags + (size_t)b*BPB*32;

  f32x4 bias4 = {0.f,0.f,0.f,0.f};
  if (kh == 0) bias4 = ((const f32x4*)(biasvP + p*PRQ))[rg];
  const float wuj = (tid < 128) ? wu[128*p + tid] : 0.f;
  const float buv = bu[0];

  float c_reg = 0.f, h_out = 0.f;             // unit (tid) state, tid<128
  float ut_r = 1.f, dot_r = 0.f;              // thread-0 scalar state
  int ustep = 0;

  if (tid < 128)
    *(f16x4*)(zs + 4*tid) = (f16x4){(_Float16)0,(_Float16)0,(_Float16)0,(_Float16)0};
  if (tid == 0) u_lds = 1;
  __syncthreads();

  for (int t0 = 0; t0 < LL; t0 += CS) {
    // ---- stage x chunk as fp16 pairs ----
    {
      const int tt = tid >> 7, kp = tid & 127;
#pragma unroll
      for (int o = 0; o < CS; o += 8) {
        const int ttt = tt + o;
        f16x2 v = {(_Float16)0, (_Float16)0};
        if (t0 + ttt < LL) {
          const float* sp = seqb + (size_t)(t0+ttt)*NB + 2*kp;
          v[0] = (_Float16)sp[0]; v[1] = (_Float16)sp[1];
        }
        seqc[ttt][kp] = v;
      }
    }
    __syncthreads();

    // ---- xp chunk GEMM: thread (rg, kh) -> rows 4rg..4rg+3, timesteps 2kh,2kh+1 --
    {
      f32x4 acc[2] = {{0,0,0,0},{0,0,0,0}};
      const f16x8* wp = (const f16x8*)wihB + rg;
#pragma unroll 4
      for (int kp = 0; kp < 128; ++kp) {
        const f16x8 w = wp[(size_t)kp*RGQ];
#pragma unroll
        for (int tt = 0; tt < 2; ++tt) {
          const f16x2 z = seqc[2*kh + tt][kp];
          acc[tt].x = FDOT2(SH(w,0), z, acc[tt].x);
          acc[tt].y = FDOT2(SH(w,1), z, acc[tt].y);
          acc[tt].z = FDOT2(SH(w,2), z, acc[tt].z);
          acc[tt].w = FDOT2(SH(w,3), z, acc[tt].w);
        }
      }
#pragma unroll
      for (int tt = 0; tt < 2; ++tt)
        *(f32x4*)&xp[2*kh + tt][4*rg] = acc[tt];
    }
    __syncthreads();

    const int tend = (t0 + CS < LL) ? t0 + CS : LL;
    for (int t = t0; t < tend; ++t) {
      const int u = u_lds;

      if (u) {
        ustep++;
        const int buf = ustep & 1;
        // ---- W_hh quarter-GEMV: k-slice kh (32 k-pairs, streamed) ----
        float a0 = 0.f, a1 = 0.f, a2 = 0.f, a3 = 0.f;
        {
          const f16x8* wp = (const f16x8*)whhB + ((size_t)(32*kh))*RGQ + rg;
          const _Float16* zp = zs + 64*kh;
#pragma unroll 8
          for (int kp = 0; kp < 32; ++kp) {
            const f16x8 w = wp[(size_t)kp*RGQ];
            const f16x2 z = *(const f16x2*)(zp + 2*kp);
            a0 = FDOT2(SH(w,0), z, a0);
            a1 = FDOT2(SH(w,1), z, a1);
            a2 = FDOT2(SH(w,2), z, a2);
            a3 = FDOT2(SH(w,3), z, a3);
          }
        }
        if (kh) part[kh-1][rg] = f32x4{a0, a1, a2, a3};
        __syncthreads();                        // (1) k-partials

        if (kh == 0) {
          f32x4 v = f32x4{a0, a1, a2, a3} + bias4 + *(const f32x4*)&xp[t - t0][4*rg];
#pragma unroll
          for (int q = 0; q < 7; ++q) v += part[q][rg];
          const int gate = rg >> 5;             // local rows 4rg..4rg+3, gate = rl>>7
          f32x4 s;
          if (gate == 2) {
            s.x = tanhf(v.x); s.y = tanhf(v.y); s.z = tanhf(v.z); s.w = tanhf(v.w);
          } else {
            s.x = sigm(v.x); s.y = sigm(v.y); s.z = sigm(v.z); s.w = sigm(v.w);
          }
          *(f32x4*)&gown[4*rg] = s;
        }
        __syncthreads();                        // (2) gown ready

        // ---- local state update: unit jj = tid (c in register) ----
        if (tid < 128) {
          const int jj = tid;
          const float ig = gown[jj],       fg = gown[128 + jj];
          const float gg = gown[256 + jj], og = gown[384 + jj];
          const float ct = fg*c_reg + ig*gg;    // u==1 exact: c = cnew
          const float ht = og * tanhf(ct);
          c_reg = ct; h_out = ht;
          const _Float16 hh = (_Float16)ht;
          zs[128*p + jj] = hh;
          st2_sys((_Float16*)(pay_own + (size_t)buf*PAYF) + jj, hh);
          float pp = ct * wuj;
#pragma unroll
          for (int off = 1; off < 64; off <<= 1) pp += __shfl_xor(pp, off);
          if ((tid & 63) == 0) {
            pw[tid >> 6] = pp;
            st4f_sys(pay_own + (size_t)buf*PAYF + 64 + (tid >> 6), pp);
          }
          asm volatile("s_waitcnt vmcnt(0)" ::: "memory");
        }
        __syncthreads();                        // (3) payload drained

        // ---- flag: store own FIRST, then poll (round-9 protocol verbatim) ----
        if (tid == 0) st4_sys_u32(flags_b + p*32, (unsigned)ustep);
        if (tid < 3) {
          const int q = (p + 1 + tid) & 3;
          const unsigned* fp = flags_b + q*32;
          unsigned f = ld4_sys_u32(fp);
          while (f < (unsigned)ustep) {
            __builtin_amdgcn_s_sleep(1);
            f = ld4_sys_u32(fp);
          }
        }
        __syncthreads();                        // (4) partners ready

        // ---- partner h-slices -> zs; tid0 assembles du dot + u decision ----
        if (tid < 48) {
          const int q = tid >> 4, o = tid & 15;
          const int p2 = (p + 1 + q) & 3;
          const float* pp2 = pay_b + ((size_t)p2*2 + buf)*PAYF;
          const f32x4 r = ld16_sys1(pp2 + o*4);
          *(f32x4*)&zs[128*p2 + o*8] = r;
        }
        if (tid == 0) {
          const int q1 = (p+1)&3, q2 = (p+2)&3, q3 = (p+3)&3;
          f32x2 r1, r2, r3;
          ld8x3_sys(pay_b + ((size_t)q1*2 + buf)*PAYF + 64,
                    pay_b + ((size_t)q2*2 + buf)*PAYF + 64,
                    pay_b + ((size_t)q3*2 + buf)*PAYF + 64, r1, r2, r3);
          float dsum[4];
          dsum[p]  = pw[0] + pw[1];
          dsum[q1] = r1.x + r1.y;
          dsum[q2] = r2.x + r2.y;
          dsum[q3] = r3.x + r3.y;
          const float dot = dsum[0] + dsum[1] + dsum[2] + dsum[3];
          const float du = sigm(dot + buv);
          ut_r = du; dot_r = dot;               // u was 1: ut_next = du exactly
          u_lds = (int)rintf(du);
        }
      } else {
        // ---- skip step: c,h,du unchanged; ut/u advance (identical in all 4) ----
        if (tid == 0) {
          const float du = sigm(dot_r + buv);
          ut_r = ut_r + fminf(du, 1.f - ut_r);
          u_lds = (int)rintf(ut_r);
        }
      }
      __syncthreads();                          // (5/end) u_lds, zs visible
    }
  }

  // each block writes ITS disjoint 128-unit slice
  if (tid < 128)
    out[(size_t)b*HID + 128*p + tid] = h_out;
}

extern "C" void kernel_launch(void* const* d_in, const int* in_sizes, int n_in,
                              void* d_out, int out_size, void* d_ws, size_t ws_size,
                              hipStream_t stream) {
  const float* x    = (const float*)d_in[0];
  const float* cw   = (const float*)d_in[1];
  const float* cb   = (const float*)d_in[2];
  const float* gma  = (const float*)d_in[3];
  const float* bta  = (const float*)d_in[4];
  const float* bmean= (const float*)d_in[5];
  const float* bvar = (const float*)d_in[6];
  const float* wih  = (const float*)d_in[7];
  const float* whh  = (const float*)d_in[8];
  const float* bih  = (const float*)d_in[9];
  const float* bhh  = (const float*)d_in[10];
  const float* wu   = (const float*)d_in[11];
  const float* bu   = (const float*)d_in[12];
  float* out = (float*)d_out;

  float* ws       = (float*)d_ws;
  float* seq      = ws;                                    // 8,355,840 f
  _Float16* whhP4 = (_Float16*)(seq + (size_t)BB*LL*NB);   // 4*262144 h (2 MB)
  _Float16* wihP4 = whhP4 + (size_t)4*NHH4;                // 4*131072 h (1 MB)
  float* biasvP   = (float*)(wihP4 + (size_t)4*NIH4);      // 2048 f
  float* pay      = biasvP + ROWS;                         // 256*2*128 f (256 KB)
  unsigned* flags = (unsigned*)(pay + (size_t)BPB*BB*2*PAYF); // 256*32 u32

  hipMemsetAsync(flags, 0, (size_t)BPB*BB*32*sizeof(unsigned), stream);

  hipLaunchKernelGGL(prep_kernel,
                     dim3((4*NHH4 + 4*NIH4 + ROWS + 255)/256), dim3(256),
                     0, stream, wih, whh, bih, bhh, whhP4, wihP4, biasvP);
  hipLaunchKernelGGL(conv_kernel, dim3(16, 64), dim3(256), 0, stream,
                     x, cw, cb, gma, bta, bmean, bvar, seq);
  hipLaunchKernelGGL(rec_kernel, dim3(BPB*BB), dim3(1024), 0, stream,
                     seq, whhP4, wihP4, biasvP, wu, bu, pay, flags, out);
}